// Round 7
// baseline (373.451 us; speedup 1.0000x reference)
//
#include <hip/hip_runtime.h>

#define T_LEN 1024
#define P_DIM 32
#define HOME_IDX 0
#define NCHUNK 32
#define CHUNK 32

// One wave (lanes 0-63) per batch runs the Viterbi recurrence; 1024
// threads/block exist only for the parallel chunked backtrack (waves 1-15
// sleep at the post-loop barrier).
//
// THIS ROUND'S single structural change vs the proven r4 kernel: the delta
// broadcast + cross-half combine (16 ds_bpermute + 2 __shfl_xor = two serial
// DS round trips per step) is replaced by an LDS restage with FULL per-lane
// reduction:
//   * delta1 (32 floats) is written to sdelta via one ds_write_b32 (lanes l
//     and l+32 write the same value to the same address - benign), then read
//     back by 8 uniform-address ds_read_b128 (LDS broadcast, conflict-free).
//     Within a single wave the DS pipe processes ops in program order, so
//     write -> read needs no barrier (the 15 parked waves couldn't join one).
//   * Each lane computes all 32 candidates c[q] = delta[q] + A[q][p] and
//     reduces lane-locally: NO cross-lane combine anywhere in the loop.
//     (permlane is abandoned after r2/r3/r5/r6: its semantics/hazards on
//     gfx950 don't match any model I can build from here.)
//   * Reads for step t+1 are issued at the END of step t, right after the
//     delta write; their latency is overlapped by the index scan.
//   * argmax: descending-j equality scan (c[j]==v1 -> ia=j) gives the FIRST
//     max index; exact because fmax returns one of its inputs bit-exactly,
//     +-0 compare equal, inputs NaN-free.
//
// Exactness notes (harness-verified across rounds):
//  * NEG = finfo(f32).min/4; ulp(NEG) >> |A|<=0.01, so NEG + A == NEG; the
//    v=0 slice is NEG except q=HOME -> v0[p] = delta0h + A[0][p], a0 = 0.
//  * use1 = (v1 > v0) strict, matching the reference.
//  * psi byte: cond = use1 || is_home; byte = cond ? (a1|32) : 0.
//  * delta0h update order preserved: (delta0h + A00) + (u[t,0] + bias0).
//
// Backtrack (PROVEN in round 4): 1023 backsteps in 32 chunks of <=32.
// Phase 1: 1024 threads build per-chunk (y,v)-maps for all 32 v=1 entry
// states. Phase 2: one thread composes maps from (last_p,1); v=0 absorbing at
// (0,0). Phase 3: 32 lanes re-walk their chunk from its true entry.
// Per-backstep rule identical to serial: if v: (y,v)=(byte&31,(byte>>5)&1)
// else (0,0); out[i] = new y.

__launch_bounds__(1024, 1)
__global__ void crf_viterbi_kernel(const float* __restrict__ U,
                                   const float* __restrict__ A,
                                   const float* __restrict__ bias,
                                   int* __restrict__ out)
{
    __shared__ __align__(16) float4 sdelta[P_DIM / 4];    // 128 B, delta stage
    __shared__ unsigned char spsi[(T_LEN - 1) * P_DIM];   // 32736 B
    __shared__ unsigned char Mmap[NCHUNK * P_DIM];        // chunk maps
    __shared__ unsigned char ent[NCHUNK];                 // chunk entry states
    __shared__ int last_p_sh;

    const int tid = threadIdx.x;
    const int b   = blockIdx.x;
    int* __restrict__ outb = out + (size_t)b * T_LEN;

    if (tid < 64) {
        const int lane = tid;
        const int p    = lane & 31;
        const float NEG = -(3.4028234663852886e38f / 4.0f);

        // Full A column: A[q][p] for q = 0..31
        float Areg[32];
#pragma unroll
        for (int q = 0; q < 32; ++q)
            Areg[q] = A[q * P_DIM + p];
        const float A0p    = Areg[0];     // A[HOME][p]
        const float A00    = A[0];        // A[HOME][HOME]
        const float bias_p = bias[p];
        const float bias0  = bias[0];
        const bool  is_home = (p == HOME_IDX);

        const float* __restrict__ Ub = U + (size_t)b * T_LEN * P_DIM;

        // t = 0 init
        const float u00 = Ub[p] + bias_p;
        float delta1  = is_home ? NEG : u00;     // v=1 slice, per-lane p
        float delta0h = Ub[HOME_IDX] + bias0;    // v=0 slice at HOME (uniform)

        // Prefetch ring, depth 4. Row t lives in slot (t-1)&3.
        float L0 = Ub[1 * P_DIM + p];
        float L1 = Ub[2 * P_DIM + p];
        float L2 = Ub[3 * P_DIM + p];
        float L3 = Ub[4 * P_DIM + p];

        float Ut_n = L0 + bias_p;          // for t = 1
        float u0_n = __shfl(Ut_n, 0);      // u[t,0] + bias0, broadcast

        // Stage initial delta and issue the first read set (in-order DS).
        ((float*)sdelta)[p] = delta1;
        float4 R0 = sdelta[0], R1 = sdelta[1], R2 = sdelta[2], R3 = sdelta[3];
        float4 R4 = sdelta[4], R5 = sdelta[5], R6 = sdelta[6], R7 = sdelta[7];

#define STEP(t, Lc, Lr) do {                                                   \
    const float Ut  = Ut_n;                                                    \
    const float u0c = u0_n;                                                    \
    Ut_n = (Lc) + bias_p;                                                      \
    u0_n = __shfl(Ut_n, 0);                                                    \
    { int tn = (t) + 4; if (tn > T_LEN - 1) tn = T_LEN - 1;                    \
      (Lr) = Ub[(size_t)tn * P_DIM + p]; }                                     \
    float c[32];                                                               \
    c[0]=R0.x+Areg[0];  c[1]=R0.y+Areg[1];  c[2]=R0.z+Areg[2];  c[3]=R0.w+Areg[3];   \
    c[4]=R1.x+Areg[4];  c[5]=R1.y+Areg[5];  c[6]=R1.z+Areg[6];  c[7]=R1.w+Areg[7];   \
    c[8]=R2.x+Areg[8];  c[9]=R2.y+Areg[9];  c[10]=R2.z+Areg[10]; c[11]=R2.w+Areg[11];\
    c[12]=R3.x+Areg[12]; c[13]=R3.y+Areg[13]; c[14]=R3.z+Areg[14]; c[15]=R3.w+Areg[15];\
    c[16]=R4.x+Areg[16]; c[17]=R4.y+Areg[17]; c[18]=R4.z+Areg[18]; c[19]=R4.w+Areg[19];\
    c[20]=R5.x+Areg[20]; c[21]=R5.y+Areg[21]; c[22]=R5.z+Areg[22]; c[23]=R5.w+Areg[23];\
    c[24]=R6.x+Areg[24]; c[25]=R6.y+Areg[25]; c[26]=R6.z+Areg[26]; c[27]=R6.w+Areg[27];\
    c[28]=R7.x+Areg[28]; c[29]=R7.y+Areg[29]; c[30]=R7.z+Areg[30]; c[31]=R7.w+Areg[31];\
    /* lane-local max over all 32 (v_max3-friendly groups of 3) */             \
    const float g0 = fmaxf(fmaxf(c[0],  c[1]),  c[2]);                         \
    const float g1 = fmaxf(fmaxf(c[3],  c[4]),  c[5]);                         \
    const float g2 = fmaxf(fmaxf(c[6],  c[7]),  c[8]);                         \
    const float g3 = fmaxf(fmaxf(c[9],  c[10]), c[11]);                        \
    const float g4 = fmaxf(fmaxf(c[12], c[13]), c[14]);                        \
    const float g5 = fmaxf(fmaxf(c[15], c[16]), c[17]);                        \
    const float g6 = fmaxf(fmaxf(c[18], c[19]), c[20]);                        \
    const float g7 = fmaxf(fmaxf(c[21], c[22]), c[23]);                        \
    const float g8 = fmaxf(fmaxf(c[24], c[25]), c[26]);                        \
    const float g9 = fmaxf(fmaxf(c[27], c[28]), c[29]);                        \
    const float s0 = fmaxf(fmaxf(g0, g1), g2);                                 \
    const float s1 = fmaxf(fmaxf(g3, g4), g5);                                 \
    const float s2 = fmaxf(fmaxf(g6, g7), g8);                                 \
    const float s3 = fmaxf(fmaxf(g9, c[30]), c[31]);                           \
    const float v1 = fmaxf(fmaxf(s0, s1), fmaxf(s2, s3));                      \
    const float v0 = delta0h + A0p;                                            \
    const bool  use1 = (v1 > v0);              /* strict, as reference */      \
    const bool  cond = use1 || is_home;                                        \
    const float sel  = cond ? v1 : v0;                                         \
    const float dn1  = sel + Ut;                                               \
    delta0h = (delta0h + A00) + u0c;                                           \
    /* restage delta and issue next step's reads (in-order DS, no barrier) */  \
    ((float*)sdelta)[p] = dn1;                                                 \
    R0 = sdelta[0]; R1 = sdelta[1]; R2 = sdelta[2]; R3 = sdelta[3];            \
    R4 = sdelta[4]; R5 = sdelta[5]; R6 = sdelta[6]; R7 = sdelta[7];            \
    /* argmax (off critical path, hides under read latency): first j == v1 */  \
    int ia = 0;                                                                \
    _Pragma("unroll")                                                          \
    for (int j = 31; j >= 0; --j)                                              \
        if (c[j] == v1) ia = j;                                                \
    spsi[(size_t)((t) - 1) * P_DIM + p] = (unsigned char)(cond ? (ia | 32) : 0); \
    delta1 = dn1;                                                              \
} while (0)

        STEP(1, L1, L0);
        STEP(2, L2, L1);
        STEP(3, L3, L2);
        for (int t = 4; t <= T_LEN - 4; t += 4) {
            STEP(t + 0, L0, L3);
            STEP(t + 1, L1, L0);
            STEP(t + 2, L2, L1);
            STEP(t + 3, L3, L2);
        }
#undef STEP

        // last_p = argmax_p delta_T[:,1], first index wins (lexicographic
        // butterfly, m<=16 mixes only within 32-lane halves; lane 0's result
        // comes from lanes 0..31 which hold delta_T[p]).
        float mv = delta1;
        int   mi = p;
#pragma unroll
        for (int m = 16; m >= 1; m >>= 1) {
            float ov = __shfl_xor(mv, m);
            int   oi = __shfl_xor(mi, m);
            bool take = (ov > mv) || ((ov == mv) && (oi < mi));
            mv = take ? ov : mv;
            mi = take ? oi : mi;
        }
        if (lane == 0) {
            outb[T_LEN - 1] = mi;
            last_p_sh = mi;
        }
    }

    __syncthreads();   // psi + last_p visible to all 16 waves

    // Phase 1: per-chunk maps. Chunk c covers backsteps i in
    // [32c, min(32c+32, 1023)). Thread (c = tid>>5, pp = tid&31) walks from
    // hypothetical entry (pp, v=1).
    {
        const int c  = tid >> 5;
        const int pp = tid & 31;
        const int i_hi = min((c + 1) * CHUNK, T_LEN - 1);
        const int i_lo = c * CHUNK;
        int y = pp, v = 1;
        for (int i = i_hi - 1; i >= i_lo; --i) {
            const int bt = spsi[i * P_DIM + y];
            const int py = v ? (bt & 31) : 0;
            const int nv = v ? ((bt >> 5) & 1) : 0;
            y = py; v = nv;
        }
        Mmap[c * P_DIM + pp] = (unsigned char)(y | (v << 5));
    }
    __syncthreads();

    // Phase 2: compose maps from the top to get each chunk's true entry state.
    if (tid == 0) {
        int y = last_p_sh, v = 1;
        for (int c = NCHUNK - 1; c >= 0; --c) {
            ent[c] = (unsigned char)(y | (v << 5));
            if (v) {
                const int m = Mmap[c * P_DIM + y];
                y = m & 31;
                v = (m >> 5) & 1;
            } else {
                y = 0; v = 0;
            }
        }
    }
    __syncthreads();

    // Phase 3: 32 lanes re-walk their chunk from the true entry, emitting out.
    if (tid < NCHUNK) {
        const int c = tid;
        const int i_hi = min((c + 1) * CHUNK, T_LEN - 1);
        const int i_lo = c * CHUNK;
        const int e = ent[c];
        int y = e & 31;
        int v = (e >> 5) & 1;
        for (int i = i_hi - 1; i >= i_lo; --i) {
            const int bt = spsi[i * P_DIM + y];
            const int py = v ? (bt & 31) : 0;
            const int nv = v ? ((bt >> 5) & 1) : 0;
            outb[i] = py;
            y = py; v = nv;
        }
    }
}

extern "C" void kernel_launch(void* const* d_in, const int* in_sizes, int n_in,
                              void* d_out, int out_size, void* d_ws, size_t ws_size,
                              hipStream_t stream) {
    const float* U    = (const float*)d_in[0];   // (B, T, P) f32
    const float* A    = (const float*)d_in[1];   // (P, P)    f32
    const float* bias = (const float*)d_in[2];   // (P,)      f32
    int* out = (int*)d_out;                      // (B, T)    int32

    const int B = in_sizes[0] / (T_LEN * P_DIM);
    crf_viterbi_kernel<<<B, 1024, 0, stream>>>(U, A, bias, out);
}